// Round 4
// baseline (115.730 us; speedup 1.0000x reference)
//
#include <hip/hip_runtime.h>
#include <hip/hip_bf16.h>
#include <stdint.h>

#define NTOK 8192
#define D_   1024
#define E_   8
#define MT   64
#define NT   128
#define BK   64
#define KK   2048
#define KSTEPS 32
#define MAX_TILES 192
#define BUF_S 12288   // shorts per LDS buffer: A 4096 + B 8192

typedef __attribute__((ext_vector_type(8))) short short8;
typedef __attribute__((ext_vector_type(4))) float f32x4;

__device__ inline unsigned short f2b(float f) {
    unsigned int u = __float_as_uint(f);
    unsigned int r = (u + 0x7fffu + ((u >> 16) & 1u)) >> 16;
    return (unsigned short)r;
}

__device__ inline uint4 pack8(float4 a, float4 b, float s) {
    return make_uint4(
        (unsigned)f2b(a.x * s) | ((unsigned)f2b(a.y * s) << 16),
        (unsigned)f2b(a.z * s) | ((unsigned)f2b(a.w * s) << 16),
        (unsigned)f2b(b.x * s) | ((unsigned)f2b(b.y * s) << 16),
        (unsigned)f2b(b.z * s) | ((unsigned)f2b(b.w * s) << 16));
}

// async global->LDS, 16B per lane; LDS dest = wave-uniform base + lane*16.
__device__ inline void gload16(const void* g, void* l) {
    __builtin_amdgcn_global_load_lds(
        (const __attribute__((address_space(1))) unsigned int*)(uintptr_t)g,
        (__attribute__((address_space(3))) unsigned int*)(unsigned int)(uintptr_t)l,
        16, 0, 0);
}

// ---------------- Phase 0+1 fused: We transpose (blocks 0..2047) || gating+cast (2048..4095) ----------------
// WeT[e][m][d] bf16;  Abf[tok][0:1024]=bf16(x*wA), [1024:2048]=bf16(x*wB)
__global__ __launch_bounds__(256) void prep_kernel(const float* __restrict__ We,
                                                   unsigned short* __restrict__ WeT,
                                                   const float* __restrict__ x,
                                                   const float* __restrict__ Wg,
                                                   int* __restrict__ g_tok,
                                                   unsigned short* __restrict__ Abf) {
    __shared__ __align__(16) float smem[8192];   // overlay: 64x65 tile | 8x1024 wgt
    int b = blockIdx.x;
    int t = threadIdx.x;
    if (b < 2048) {
        // ---- We (E,D,D) f32 -> WeT (E,M,D) bf16 ----
        float (*tile)[65] = reinterpret_cast<float (*)[65]>(smem);
        int e = b >> 8, rem = b & 255;
        int m0 = (rem & 15) * 64, d0 = (rem >> 4) * 64;
        const float* src = We + ((size_t)e << 20);
        int r = t >> 4, c4 = (t & 15) * 4;
        #pragma unroll
        for (int i = 0; i < 4; i++) {
            int d = r + i * 16;
            float4 v = *reinterpret_cast<const float4*>(src + (size_t)(d0 + d) * D_ + m0 + c4);
            tile[d][c4 + 0] = v.x; tile[d][c4 + 1] = v.y;
            tile[d][c4 + 2] = v.z; tile[d][c4 + 3] = v.w;
        }
        __syncthreads();
        int m = t >> 2, dq = (t & 3) * 16;
        unsigned int pack[8];
        #pragma unroll
        for (int j = 0; j < 16; j += 2) {
            pack[j >> 1] = (unsigned int)f2b(tile[dq + j][m]) |
                           ((unsigned int)f2b(tile[dq + j + 1][m]) << 16);
        }
        uint4* dst = reinterpret_cast<uint4*>(WeT + ((size_t)e << 20) + (size_t)(m0 + m) * D_ + d0 + dq);
        dst[0] = make_uint4(pack[0], pack[1], pack[2], pack[3]);
        dst[1] = make_uint4(pack[4], pack[5], pack[6], pack[7]);
    } else {
        // ---- gating + weighted bf16 cast ----
        float* wgt = smem;   // transposed: wgt[e*1024 + d]
        for (int i = t; i < 8192; i += 256) wgt[(i & 7) * 1024 + (i >> 3)] = Wg[i];
        __syncthreads();
        int wave = t >> 6, lane = t & 63;
        int tok = (b - 2048) * 4 + wave;
        const float* xr = x + (size_t)tok * D_;

        float acc[8] = {0.f, 0.f, 0.f, 0.f, 0.f, 0.f, 0.f, 0.f};
        for (int i = 0; i < 16; i++) {
            int d = i * 64 + lane;
            float xv = xr[d];
            #pragma unroll
            for (int e = 0; e < 8; e++) acc[e] += xv * wgt[e * 1024 + d];
        }
        #pragma unroll
        for (int e = 0; e < 8; e++)
            #pragma unroll
            for (int off = 32; off > 0; off >>= 1)
                acc[e] += __shfl_xor(acc[e], off, 64);

        float best = acc[0]; int bi = 0;
        #pragma unroll
        for (int e = 1; e < 8; e++) { if (acc[e] > best) { best = acc[e]; bi = e; } }
        float second = -3.4e38f; int si = 0;
        #pragma unroll
        for (int e = 0; e < 8; e++) { if (e != bi && acc[e] > second) { second = acc[e]; si = e; } }
        float eb = __expf(second - best);
        float w0 = 1.f / (1.f + eb);
        float w1 = eb / (1.f + eb);
        int ea, ebx; float wA, wB;
        if (bi < si) { ea = bi; ebx = si; wA = w0; wB = w1; }
        else         { ea = si; ebx = bi; wA = w1; wB = w0; }
        if (lane == 0) g_tok[tok] = ea * 8 + ebx;

        const float4* xv4 = reinterpret_cast<const float4*>(xr + lane * 16);
        float4 v0 = xv4[0], v1 = xv4[1], v2 = xv4[2], v3 = xv4[3];
        unsigned short* rowp = Abf + (size_t)tok * KK + lane * 16;
        *reinterpret_cast<uint4*>(rowp)        = pack8(v0, v1, wA);
        *reinterpret_cast<uint4*>(rowp + 8)    = pack8(v2, v3, wA);
        *reinterpret_cast<uint4*>(rowp + 1024) = pack8(v0, v1, wB);
        *reinterpret_cast<uint4*>(rowp + 1032) = pack8(v2, v3, wB);
    }
}

// ---------------- Phase 2: routing (bucket by expert pair + tile schedule) ----------------
__global__ __launch_bounds__(1024) void route_kernel(const int* __restrict__ g_tok,
                                                     int* __restrict__ token_list,
                                                     int4* __restrict__ tile_desc,
                                                     int* __restrict__ n_tiles_out) {
    __shared__ int cnt[64], pos[64], start[64];
    int t = threadIdx.x;
    if (t < 64) cnt[t] = 0;
    __syncthreads();
    for (int i = t; i < NTOK; i += 1024) atomicAdd(&cnt[g_tok[i]], 1);
    __syncthreads();
    if (t == 0) {
        int run = 0, nt = 0;
        for (int g = 0; g < 64; g++) {
            start[g] = run;
            int c = cnt[g];
            int off = 0;
            while (off < c) {
                int rows = (c - off < MT) ? (c - off) : MT;
                tile_desc[nt++] = make_int4(run + off, rows, g >> 3, g & 7);
                off += MT;
            }
            run += c;
        }
        *n_tiles_out = nt;
    }
    __syncthreads();
    if (t < 64) pos[t] = start[t];
    __syncthreads();
    for (int i = t; i < NTOK; i += 1024) {
        int p = atomicAdd(&pos[g_tok[i]], 1);
        token_list[p] = i;
    }
}

// ---------------- Phase 3: grouped GEMM — 3-deep pipeline, counted vmcnt, XOR swizzle ----------------
// 1-D grid, b = (tile&7) + 8*colblk + 64*(tile>>3): all 8 colblks of a tile land on
// XCD tile%8 (round-robin dispatch) and adjacent in dispatch order -> A-tile L2 reuse.
__global__ __launch_bounds__(256, 2) void moe_gemm(const unsigned short* __restrict__ Abf,
                                                   const unsigned short* __restrict__ WeT,
                                                   const int* __restrict__ token_list,
                                                   const int4* __restrict__ tile_desc,
                                                   const int* __restrict__ n_tiles,
                                                   float* __restrict__ out) {
    int b = blockIdx.x;
    int tile = ((b >> 6) << 3) | (b & 7);
    int ncol0 = ((b >> 3) & 7) * NT;
    if (tile >= *n_tiles) return;
    int4 dsc = tile_desc[tile];
    int loff = dsc.x, rows = dsc.y, ea = dsc.z, ebx = dsc.w;

    __shared__ __align__(16) unsigned short lds[3 * BUF_S];  // 72 KB
    __shared__ int tokOut[MT];
    __shared__ int tokStage[MT];

    int t = threadIdx.x;
    int wave = t >> 6, lane = t & 63;

    if (t < MT) {
        int tk = token_list[loff + ((t < rows) ? t : 0)];
        tokStage[t] = tk;
        tokOut[t] = (t < rows) ? tk : -1;
    }
    __syncthreads();

    // per-thread staging sources (swizzle folded into global address; LDS dest stays linear)
    int swz8 = (((t & 7) ^ ((t >> 3) & 7)) << 3);
    const unsigned short* asrc0 = Abf + (size_t)tokStage[t >> 3] * KK + swz8;
    const unsigned short* asrc1 = Abf + (size_t)tokStage[32 + (t >> 3)] * KK + swz8;
    const unsigned short* wbase = WeT + ((size_t)ea << 20);
    size_t ebd = ((size_t)(ebx - ea)) << 20;
    const unsigned short* bsrc0 = wbase + (size_t)(ncol0 +  0 + (t >> 3)) * D_ + swz8;
    const unsigned short* bsrc1 = wbase + (size_t)(ncol0 + 32 + (t >> 3)) * D_ + swz8;
    const unsigned short* bsrc2 = wbase + (size_t)(ncol0 + 64 + (t >> 3)) * D_ + swz8;
    const unsigned short* bsrc3 = wbase + (size_t)(ncol0 + 96 + (t >> 3)) * D_ + swz8;

    int wu = wave * 512;   // wave-uniform LDS chunk base (shorts)
    auto stage = [&](int ks, int buf) {
        unsigned short* base = &lds[buf * BUF_S];
        int k0 = ks * BK;
        size_t eoff = (k0 < D_) ? (size_t)k0 : (size_t)(k0 - D_) + ebd;
        gload16(asrc0 + k0,   base + wu);
        gload16(asrc1 + k0,   base + 2048 + wu);
        gload16(bsrc0 + eoff, base + 4096 + wu);
        gload16(bsrc1 + eoff, base + 6144 + wu);
        gload16(bsrc2 + eoff, base + 8192 + wu);
        gload16(bsrc3 + eoff, base + 10240 + wu);
    };

    // wave grid 2(M) x 2(N); wave-tile 32x64
    int wm = (wave >> 1) * 32, wn = (wave & 1) * 64;
    int l15 = lane & 15, hi = lane >> 4, lo7 = lane & 7;
    int rA0 = (wm + l15) * BK;
    int rA1 = rA0 + 16 * BK;
    int cB0 = (wn + l15) * BK + 4096;
    int s0 = ((hi) ^ lo7) << 3;          // ksub 0 slot offset (shorts)
    int s1 = ((4 + hi) ^ lo7) << 3;      // ksub 1

    f32x4 acc[2][4];
    #pragma unroll
    for (int m = 0; m < 2; m++)
        #pragma unroll
        for (int n = 0; n < 4; n++) acc[m][n] = (f32x4){0.f, 0.f, 0.f, 0.f};

    stage(0, 0);
    stage(1, 1);
    int cur = 0;
    for (int ks = 0; ks < KSTEPS; ++ks) {
        if (ks < KSTEPS - 1) { asm volatile("s_waitcnt vmcnt(6)" ::: "memory"); }
        else                 { asm volatile("s_waitcnt vmcnt(0)" ::: "memory"); }
        __builtin_amdgcn_s_barrier();
        if (ks < KSTEPS - 2) {
            int b2 = cur + 2; if (b2 >= 3) b2 -= 3;
            stage(ks + 2, b2);
        }
        const unsigned short* Ab = &lds[cur * BUF_S];
        const unsigned short* Bb = Ab;  // B region at +4096, folded into cB
        #pragma unroll
        for (int ksub = 0; ksub < 2; ++ksub) {
            int s = ksub ? s1 : s0;
            short8 a0 = *reinterpret_cast<const short8*>(&Ab[rA0 + s]);
            short8 a1 = *reinterpret_cast<const short8*>(&Ab[rA1 + s]);
            #pragma unroll
            for (int n = 0; n < 4; n++) {
                short8 bfr = *reinterpret_cast<const short8*>(&Bb[cB0 + n * (16 * BK) + s]);
                acc[0][n] = __builtin_amdgcn_mfma_f32_16x16x32_bf16(a0, bfr, acc[0][n], 0, 0, 0);
                acc[1][n] = __builtin_amdgcn_mfma_f32_16x16x32_bf16(a1, bfr, acc[1][n], 0, 0, 0);
            }
        }
        cur = (cur == 2) ? 0 : cur + 1;
    }

    // epilogue: single writer per out row, weights already folded in
    int q4 = hi * 4;
    #pragma unroll
    for (int m = 0; m < 2; m++) {
        #pragma unroll
        for (int n = 0; n < 4; n++) {
            int col = ncol0 + wn + n * 16 + l15;
            #pragma unroll
            for (int j = 0; j < 4; j++) {
                int r = wm + m * 16 + q4 + j;
                int tk = tokOut[r];
                if (tk >= 0) out[(size_t)tk * D_ + col] = acc[m][n][j];
            }
        }
    }
}

extern "C" void kernel_launch(void* const* d_in, const int* in_sizes, int n_in,
                              void* d_out, int out_size, void* d_ws, size_t ws_size,
                              hipStream_t stream) {
    const float* x  = (const float*)d_in[0];
    const float* Wg = (const float*)d_in[1];
    const float* We = (const float*)d_in[2];
    float* out = (float*)d_out;

    size_t off = 0;
    auto alloc = [&](size_t bytes) -> void* {
        void* p = (char*)d_ws + off;
        off += (bytes + 255) & ~(size_t)255;
        return p;
    };
    unsigned short* WeT  = (unsigned short*)alloc((size_t)E_ * 1024 * 1024 * 2);  // 16 MB
    unsigned short* Abf  = (unsigned short*)alloc((size_t)NTOK * KK * 2);         // 33.5 MB
    int*   g_tok      = (int*)  alloc(NTOK * 4);
    int*   token_list = (int*)  alloc(NTOK * 4);
    int4*  tile_desc  = (int4*) alloc(MAX_TILES * 16);
    int*   n_tiles    = (int*)  alloc(4);

    prep_kernel<<<4096, 256, 0, stream>>>(We, WeT, x, Wg, g_tok, Abf);
    route_kernel<<<1, 1024, 0, stream>>>(g_tok, token_list, tile_desc, n_tiles);
    moe_gemm<<<64 * (MAX_TILES / 8), 256, 0, stream>>>(Abf, WeT, token_list,
                                                       tile_desc, n_tiles, out);
}

// Round 5
// 114.119 us; speedup vs baseline: 1.0141x; 1.0141x over previous
//
#include <hip/hip_runtime.h>
#include <hip/hip_bf16.h>
#include <stdint.h>

#define NTOK 8192
#define D_   1024
#define E_   8
#define MT   64
#define NT   128
#define BK   64
#define KSTEPS 32
#define MAX_TILES 192
#define BUF_S 12288   // shorts per LDS buffer: A 4096 + B 8192

typedef __attribute__((ext_vector_type(8))) short short8;
typedef __attribute__((ext_vector_type(4))) float f32x4;

__device__ inline unsigned short f2b(float f) {
    unsigned int u = __float_as_uint(f);
    unsigned int r = (u + 0x7fffu + ((u >> 16) & 1u)) >> 16;
    return (unsigned short)r;
}

// async global->LDS, 16B per lane; LDS dest = wave-uniform base + lane*16.
__device__ inline void gload16(const void* g, void* l) {
    __builtin_amdgcn_global_load_lds(
        (const __attribute__((address_space(1))) unsigned int*)(uintptr_t)g,
        (__attribute__((address_space(3))) unsigned int*)(unsigned int)(uintptr_t)l,
        16, 0, 0);
}

// ---------------- Phase 0+1 fused: We transpose (blocks 0..2047) || gating+cast (2048..4095) ----------------
// WeT[e][m][d] bf16;  Abf[tok][d] = bf16(x[tok][d])  (unweighted, token order)
__global__ __launch_bounds__(256) void prep_kernel(const float* __restrict__ We,
                                                   unsigned short* __restrict__ WeT,
                                                   const float* __restrict__ x,
                                                   const float* __restrict__ Wg,
                                                   int* __restrict__ g_tok,
                                                   float* __restrict__ wA_tok,
                                                   float* __restrict__ wB_tok,
                                                   unsigned short* __restrict__ Abf) {
    __shared__ __align__(16) float smem[8192];   // overlay: 64x65 tile | 8x1024 wgt
    int b = blockIdx.x;
    int t = threadIdx.x;
    if (b < 2048) {
        // ---- We (E,D,D) f32 -> WeT (E,M,D) bf16 ----
        float (*tile)[65] = reinterpret_cast<float (*)[65]>(smem);
        int e = b >> 8, rem = b & 255;
        int m0 = (rem & 15) * 64, d0 = (rem >> 4) * 64;
        const float* src = We + ((size_t)e << 20);
        int r = t >> 4, c4 = (t & 15) * 4;
        #pragma unroll
        for (int i = 0; i < 4; i++) {
            int d = r + i * 16;
            float4 v = *reinterpret_cast<const float4*>(src + (size_t)(d0 + d) * D_ + m0 + c4);
            tile[d][c4 + 0] = v.x; tile[d][c4 + 1] = v.y;
            tile[d][c4 + 2] = v.z; tile[d][c4 + 3] = v.w;
        }
        __syncthreads();
        int m = t >> 2, dq = (t & 3) * 16;
        unsigned int pack[8];
        #pragma unroll
        for (int j = 0; j < 16; j += 2) {
            pack[j >> 1] = (unsigned int)f2b(tile[dq + j][m]) |
                           ((unsigned int)f2b(tile[dq + j + 1][m]) << 16);
        }
        uint4* dst = reinterpret_cast<uint4*>(WeT + ((size_t)e << 20) + (size_t)(m0 + m) * D_ + d0 + dq);
        dst[0] = make_uint4(pack[0], pack[1], pack[2], pack[3]);
        dst[1] = make_uint4(pack[4], pack[5], pack[6], pack[7]);
    } else {
        // ---- gating + unweighted bf16 cast (x read once, vectorized) ----
        float* wgt = smem;   // transposed: wgt[e*1024 + d]
        for (int i = t; i < 8192; i += 256) wgt[(i & 7) * 1024 + (i >> 3)] = Wg[i];
        __syncthreads();
        int wave = t >> 6, lane = t & 63;
        int tok = (b - 2048) * 4 + wave;
        const float* xr = x + (size_t)tok * D_;

        float4 xv[4];
        float acc[8] = {0.f, 0.f, 0.f, 0.f, 0.f, 0.f, 0.f, 0.f};
        #pragma unroll
        for (int i = 0; i < 4; i++) {
            int d0 = i * 256 + lane * 4;
            xv[i] = *reinterpret_cast<const float4*>(xr + d0);
            #pragma unroll
            for (int e = 0; e < 8; e++) {
                float4 w = *reinterpret_cast<const float4*>(&wgt[e * 1024 + d0]);
                acc[e] += xv[i].x * w.x + xv[i].y * w.y + xv[i].z * w.z + xv[i].w * w.w;
            }
        }
        #pragma unroll
        for (int e = 0; e < 8; e++)
            #pragma unroll
            for (int off = 32; off > 0; off >>= 1)
                acc[e] += __shfl_xor(acc[e], off, 64);

        float best = acc[0]; int bi = 0;
        #pragma unroll
        for (int e = 1; e < 8; e++) { if (acc[e] > best) { best = acc[e]; bi = e; } }
        float second = -3.4e38f; int si = 0;
        #pragma unroll
        for (int e = 0; e < 8; e++) { if (e != bi && acc[e] > second) { second = acc[e]; si = e; } }
        float eb = __expf(second - best);
        eb = fmaxf(eb, 1e-20f);
        float w0 = 1.f / (1.f + eb);   // weight of best
        float w1 = eb / (1.f + eb);    // weight of second
        int ea, ebx; float wA, wB;
        if (bi < si) { ea = bi; ebx = si; wA = w0; wB = w1; }
        else         { ea = si; ebx = bi; wA = w1; wB = w0; }
        if (lane == 0) {
            g_tok[tok] = ea * 8 + ebx;
            wA_tok[tok] = wA;
            wB_tok[tok] = wB;
        }

        // cast the 16 already-loaded values
        unsigned short* rowp = Abf + (size_t)tok * D_;
        #pragma unroll
        for (int i = 0; i < 4; i++) {
            int d0 = i * 256 + lane * 4;
            uint2 p;
            p.x = (unsigned)f2b(xv[i].x) | ((unsigned)f2b(xv[i].y) << 16);
            p.y = (unsigned)f2b(xv[i].z) | ((unsigned)f2b(xv[i].w) << 16);
            *reinterpret_cast<uint2*>(rowp + d0) = p;
        }
    }
}

// ---------------- Phase 2: routing (bucket by expert pair + tile schedule) ----------------
__global__ __launch_bounds__(1024) void route_kernel(const int* __restrict__ g_tok,
                                                     const float* __restrict__ wA_tok,
                                                     const float* __restrict__ wB_tok,
                                                     int* __restrict__ token_list,
                                                     float* __restrict__ wA_s,
                                                     float* __restrict__ wB_s,
                                                     int4* __restrict__ tile_desc,
                                                     int* __restrict__ n_tiles_out) {
    __shared__ int cnt[64], pos[64], start[64];
    int t = threadIdx.x;
    if (t < 64) cnt[t] = 0;
    __syncthreads();
    for (int i = t; i < NTOK; i += 1024) atomicAdd(&cnt[g_tok[i]], 1);
    __syncthreads();
    if (t == 0) {
        int run = 0, nt = 0;
        for (int g = 0; g < 64; g++) {
            start[g] = run;
            int c = cnt[g];
            int off = 0;
            while (off < c) {
                int rows = (c - off < MT) ? (c - off) : MT;
                tile_desc[nt++] = make_int4(run + off, rows, g >> 3, g & 7);
                off += MT;
            }
            run += c;
        }
        *n_tiles_out = nt;
    }
    __syncthreads();
    if (t < 64) pos[t] = start[t];
    __syncthreads();
    for (int i = t; i < NTOK; i += 1024) {
        int p = atomicAdd(&pos[g_tok[i]], 1);
        token_list[p] = i;
        wA_s[p] = wA_tok[i];
        wB_s[p] = wB_tok[i];
    }
}

// ---------------- Phase 3: grouped GEMM — sequential expert halves over shared A ----------------
// Grid dim3(8, tiles): linear id = tile*8+colblk -> XCD = colblk (round-robin):
// each XCD holds a fixed 128-col slice of all experts (2 MB, L2-resident B).
// Half a (ks 0..15): B = expert ea;  half b (ks 16..31): B = expert ebx, SAME A
// addresses (L2 hit). acc rescaled by wA/wB between halves; epilogue * wB.
__global__ __launch_bounds__(256, 2) void moe_gemm(const unsigned short* __restrict__ Abf,
                                                   const unsigned short* __restrict__ WeT,
                                                   const int* __restrict__ token_list,
                                                   const float* __restrict__ wA_s,
                                                   const float* __restrict__ wB_s,
                                                   const int4* __restrict__ tile_desc,
                                                   const int* __restrict__ n_tiles,
                                                   float* __restrict__ out) {
    int tile = blockIdx.y;
    if (tile >= *n_tiles) return;
    int4 dsc = tile_desc[tile];
    int loff = dsc.x, rows = dsc.y, ea = dsc.z, ebx = dsc.w;
    int ncol0 = blockIdx.x * NT;

    __shared__ __align__(16) unsigned short lds[3 * BUF_S];  // 72 KB
    __shared__ int tokOut[MT];
    __shared__ int tokStage[MT];
    __shared__ float rat[MT], wBsh[MT];

    int t = threadIdx.x;
    int wave = t >> 6, lane = t & 63;

    if (t < MT) {
        int idx = loff + ((t < rows) ? t : 0);
        int tk = token_list[idx];
        tokStage[t] = tk;
        tokOut[t] = (t < rows) ? tk : -1;
        float wa = wA_s[idx], wb = wB_s[idx];
        wBsh[t] = wb;
        rat[t] = wa / fmaxf(wb, 1e-30f);
    }
    __syncthreads();

    // per-thread staging sources (swizzle folded into global address; LDS dest stays linear)
    int swz8 = (((t & 7) ^ ((t >> 3) & 7)) << 3);
    const unsigned short* asrc0 = Abf + (size_t)tokStage[t >> 3] * D_ + swz8;
    const unsigned short* asrc1 = Abf + (size_t)tokStage[32 + (t >> 3)] * D_ + swz8;
    const unsigned short* wbase = WeT + ((size_t)ea << 20);
    size_t ebd = ((size_t)(ebx - ea)) << 20;
    const unsigned short* bsrc0 = wbase + (size_t)(ncol0 +  0 + (t >> 3)) * D_ + swz8;
    const unsigned short* bsrc1 = wbase + (size_t)(ncol0 + 32 + (t >> 3)) * D_ + swz8;
    const unsigned short* bsrc2 = wbase + (size_t)(ncol0 + 64 + (t >> 3)) * D_ + swz8;
    const unsigned short* bsrc3 = wbase + (size_t)(ncol0 + 96 + (t >> 3)) * D_ + swz8;

    int wu = wave * 512;   // wave-uniform LDS chunk base (shorts)
    auto stage = [&](int ks, int buf) {
        unsigned short* base = &lds[buf * BUF_S];
        int k0 = (ks & 15) * BK;
        size_t boff = (size_t)k0 + ((ks < 16) ? 0 : ebd);
        gload16(asrc0 + k0,   base + wu);
        gload16(asrc1 + k0,   base + 2048 + wu);
        gload16(bsrc0 + boff, base + 4096 + wu);
        gload16(bsrc1 + boff, base + 6144 + wu);
        gload16(bsrc2 + boff, base + 8192 + wu);
        gload16(bsrc3 + boff, base + 10240 + wu);
    };

    // wave grid 2(M) x 2(N); wave-tile 32x64
    int wm = (wave >> 1) * 32, wn = (wave & 1) * 64;
    int l15 = lane & 15, hi = lane >> 4, lo7 = lane & 7;
    int rA0 = (wm + l15) * BK;
    int rA1 = rA0 + 16 * BK;
    int cB0 = (wn + l15) * BK + 4096;
    int s0 = ((hi) ^ lo7) << 3;          // ksub 0 slot offset (shorts)
    int s1 = ((4 + hi) ^ lo7) << 3;      // ksub 1
    int q4 = hi * 4;

    f32x4 acc[2][4];
    #pragma unroll
    for (int m = 0; m < 2; m++)
        #pragma unroll
        for (int n = 0; n < 4; n++) acc[m][n] = (f32x4){0.f, 0.f, 0.f, 0.f};

    stage(0, 0);
    stage(1, 1);
    int cur = 0;
    for (int ks = 0; ks < KSTEPS; ++ks) {
        if (ks < KSTEPS - 1) { asm volatile("s_waitcnt vmcnt(6)" ::: "memory"); }
        else                 { asm volatile("s_waitcnt vmcnt(0)" ::: "memory"); }
        __builtin_amdgcn_s_barrier();
        if (ks < KSTEPS - 2) {
            int b2 = cur + 2; if (b2 >= 3) b2 -= 3;
            stage(ks + 2, b2);
        }
        if (ks == 16) {
            // expert switch: acc_a *= wA/wB per row; epilogue multiplies by wB
            #pragma unroll
            for (int m = 0; m < 2; m++) {
                #pragma unroll
                for (int j = 0; j < 4; j++) {
                    float rr = rat[wm + m * 16 + q4 + j];
                    #pragma unroll
                    for (int n = 0; n < 4; n++) acc[m][n][j] *= rr;
                }
            }
        }
        const unsigned short* Ab = &lds[cur * BUF_S];
        const unsigned short* Bb = Ab;  // B region at +4096, folded into cB
        #pragma unroll
        for (int ksub = 0; ksub < 2; ++ksub) {
            int s = ksub ? s1 : s0;
            short8 a0 = *reinterpret_cast<const short8*>(&Ab[rA0 + s]);
            short8 a1 = *reinterpret_cast<const short8*>(&Ab[rA1 + s]);
            #pragma unroll
            for (int n = 0; n < 4; n++) {
                short8 bfr = *reinterpret_cast<const short8*>(&Bb[cB0 + n * (16 * BK) + s]);
                acc[0][n] = __builtin_amdgcn_mfma_f32_16x16x32_bf16(a0, bfr, acc[0][n], 0, 0, 0);
                acc[1][n] = __builtin_amdgcn_mfma_f32_16x16x32_bf16(a1, bfr, acc[1][n], 0, 0, 0);
            }
        }
        cur = (cur == 2) ? 0 : cur + 1;
    }

    // epilogue: single writer per out row; out = acc * wB
    #pragma unroll
    for (int m = 0; m < 2; m++) {
        #pragma unroll
        for (int n = 0; n < 4; n++) {
            int col = ncol0 + wn + n * 16 + l15;
            #pragma unroll
            for (int j = 0; j < 4; j++) {
                int r = wm + m * 16 + q4 + j;
                int tk = tokOut[r];
                if (tk >= 0) out[(size_t)tk * D_ + col] = acc[m][n][j] * wBsh[r];
            }
        }
    }
}

extern "C" void kernel_launch(void* const* d_in, const int* in_sizes, int n_in,
                              void* d_out, int out_size, void* d_ws, size_t ws_size,
                              hipStream_t stream) {
    const float* x  = (const float*)d_in[0];
    const float* Wg = (const float*)d_in[1];
    const float* We = (const float*)d_in[2];
    float* out = (float*)d_out;

    size_t off = 0;
    auto alloc = [&](size_t bytes) -> void* {
        void* p = (char*)d_ws + off;
        off += (bytes + 255) & ~(size_t)255;
        return p;
    };
    unsigned short* WeT  = (unsigned short*)alloc((size_t)E_ * 1024 * 1024 * 2);  // 16 MB
    unsigned short* Abf  = (unsigned short*)alloc((size_t)NTOK * D_ * 2);         // 16.8 MB
    int*   g_tok      = (int*)  alloc(NTOK * 4);
    float* wA_tok     = (float*)alloc(NTOK * 4);
    float* wB_tok     = (float*)alloc(NTOK * 4);
    int*   token_list = (int*)  alloc(NTOK * 4);
    float* wA_s       = (float*)alloc(NTOK * 4);
    float* wB_s       = (float*)alloc(NTOK * 4);
    int4*  tile_desc  = (int4*) alloc(MAX_TILES * 16);
    int*   n_tiles    = (int*)  alloc(4);

    prep_kernel<<<4096, 256, 0, stream>>>(We, WeT, x, Wg, g_tok, wA_tok, wB_tok, Abf);
    route_kernel<<<1, 1024, 0, stream>>>(g_tok, wA_tok, wB_tok,
                                         token_list, wA_s, wB_s, tile_desc, n_tiles);
    moe_gemm<<<dim3(8, MAX_TILES), 256, 0, stream>>>(Abf, WeT, token_list, wA_s, wB_s,
                                                     tile_desc, n_tiles, out);
}

// Round 6
// 100.871 us; speedup vs baseline: 1.1473x; 1.1313x over previous
//
#include <hip/hip_runtime.h>
#include <hip/hip_bf16.h>
#include <stdint.h>

#define NTOK 8192
#define D_   1024
#define E_   8
#define MT   64
#define NT   128
#define BK   64
#define KSTEPS 32
#define MAX_TILES 192
#define BUF_S 12288   // shorts per LDS buffer: A 4096 + B 8192

typedef __attribute__((ext_vector_type(8))) short short8;
typedef __attribute__((ext_vector_type(4))) float f32x4;

__device__ inline unsigned short f2b(float f) {
    unsigned int u = __float_as_uint(f);
    unsigned int r = (u + 0x7fffu + ((u >> 16) & 1u)) >> 16;
    return (unsigned short)r;
}

// async global->LDS, 16B per lane; LDS dest = wave-uniform base + lane*16.
__device__ inline void gload16(const void* g, void* l) {
    __builtin_amdgcn_global_load_lds(
        (const __attribute__((address_space(1))) unsigned int*)(uintptr_t)g,
        (__attribute__((address_space(3))) unsigned int*)(unsigned int)(uintptr_t)l,
        16, 0, 0);
}

// ---------------- Phase 0+1 fused: We transpose (blocks 0..2047) || gating+cast (2048..2303) ----------------
// WeT[e][m][d] bf16;  Abf[tok][d] = bf16(x[tok][d])  (unweighted, token order)
__global__ __launch_bounds__(256) void prep_kernel(const float* __restrict__ We,
                                                   unsigned short* __restrict__ WeT,
                                                   const float* __restrict__ x,
                                                   const float* __restrict__ Wg,
                                                   int* __restrict__ g_tok,
                                                   float* __restrict__ wA_tok,
                                                   float* __restrict__ wB_tok,
                                                   unsigned short* __restrict__ Abf) {
    __shared__ __align__(16) float smem[8192];   // overlay: 64x65 tile | 8x1024 wgt
    int b = blockIdx.x;
    int t = threadIdx.x;
    if (b < 2048) {
        // ---- We (E,D,D) f32 -> WeT (E,M,D) bf16 ----
        float (*tile)[65] = reinterpret_cast<float (*)[65]>(smem);
        int e = b >> 8, rem = b & 255;
        int m0 = (rem & 15) * 64, d0 = (rem >> 4) * 64;
        const float* src = We + ((size_t)e << 20);
        int r = t >> 4, c4 = (t & 15) * 4;
        #pragma unroll
        for (int i = 0; i < 4; i++) {
            int d = r + i * 16;
            float4 v = *reinterpret_cast<const float4*>(src + (size_t)(d0 + d) * D_ + m0 + c4);
            tile[d][c4 + 0] = v.x; tile[d][c4 + 1] = v.y;
            tile[d][c4 + 2] = v.z; tile[d][c4 + 3] = v.w;
        }
        __syncthreads();
        int m = t >> 2, dq = (t & 3) * 16;
        unsigned int pack[8];
        #pragma unroll
        for (int j = 0; j < 16; j += 2) {
            pack[j >> 1] = (unsigned int)f2b(tile[dq + j][m]) |
                           ((unsigned int)f2b(tile[dq + j + 1][m]) << 16);
        }
        uint4* dst = reinterpret_cast<uint4*>(WeT + ((size_t)e << 20) + (size_t)(m0 + m) * D_ + d0 + dq);
        dst[0] = make_uint4(pack[0], pack[1], pack[2], pack[3]);
        dst[1] = make_uint4(pack[4], pack[5], pack[6], pack[7]);
    } else {
        // ---- gating + unweighted bf16 cast; 32 tokens per block (Wg smem fill amortized) ----
        float* wgt = smem;   // transposed: wgt[e*1024 + d]
        for (int i = t; i < 8192; i += 256) wgt[(i & 7) * 1024 + (i >> 3)] = Wg[i];
        __syncthreads();
        int wave = t >> 6, lane = t & 63;
        int tok0 = (b - 2048) * 32 + wave * 8;

        for (int tki = 0; tki < 8; tki++) {
            int tok = tok0 + tki;
            const float* xr = x + (size_t)tok * D_;

            float4 xv[4];
            float acc[8] = {0.f, 0.f, 0.f, 0.f, 0.f, 0.f, 0.f, 0.f};
            #pragma unroll
            for (int i = 0; i < 4; i++) {
                int d0 = i * 256 + lane * 4;
                xv[i] = *reinterpret_cast<const float4*>(xr + d0);
                #pragma unroll
                for (int e = 0; e < 8; e++) {
                    float4 w = *reinterpret_cast<const float4*>(&wgt[e * 1024 + d0]);
                    acc[e] += xv[i].x * w.x + xv[i].y * w.y + xv[i].z * w.z + xv[i].w * w.w;
                }
            }
            #pragma unroll
            for (int e = 0; e < 8; e++)
                #pragma unroll
                for (int off = 32; off > 0; off >>= 1)
                    acc[e] += __shfl_xor(acc[e], off, 64);

            float best = acc[0]; int bi = 0;
            #pragma unroll
            for (int e = 1; e < 8; e++) { if (acc[e] > best) { best = acc[e]; bi = e; } }
            float second = -3.4e38f; int si = 0;
            #pragma unroll
            for (int e = 0; e < 8; e++) { if (e != bi && acc[e] > second) { second = acc[e]; si = e; } }
            float eb = __expf(second - best);
            eb = fmaxf(eb, 1e-20f);
            float w0 = 1.f / (1.f + eb);   // weight of best
            float w1 = eb / (1.f + eb);    // weight of second
            int ea, ebx; float wA, wB;
            if (bi < si) { ea = bi; ebx = si; wA = w0; wB = w1; }
            else         { ea = si; ebx = bi; wA = w1; wB = w0; }
            if (lane == 0) {
                g_tok[tok] = ea * 8 + ebx;
                wA_tok[tok] = wA;
                wB_tok[tok] = wB;
            }

            // cast the 16 already-loaded values
            unsigned short* rowp = Abf + (size_t)tok * D_;
            #pragma unroll
            for (int i = 0; i < 4; i++) {
                int d0 = i * 256 + lane * 4;
                uint2 p;
                p.x = (unsigned)f2b(xv[i].x) | ((unsigned)f2b(xv[i].y) << 16);
                p.y = (unsigned)f2b(xv[i].z) | ((unsigned)f2b(xv[i].w) << 16);
                *reinterpret_cast<uint2*>(rowp + d0) = p;
            }
        }
    }
}

// ---------------- Phase 2: routing — 64 parallel blocks, deterministic stable compaction ----------------
// Block g: local histogram of all 64 buckets (for prefix), then stable-compacts bucket g.
__global__ __launch_bounds__(256) void route_kernel(const int* __restrict__ g_tok,
                                                    const float* __restrict__ wA_tok,
                                                    const float* __restrict__ wB_tok,
                                                    int* __restrict__ token_list,
                                                    float* __restrict__ wA_s,
                                                    float* __restrict__ wB_s,
                                                    int4* __restrict__ tile_desc,
                                                    int* __restrict__ n_tiles_out) {
    int g = blockIdx.x;    // 0..63
    int t = threadIdx.x;   // 0..255
    __shared__ int cnt[64];
    __shared__ int pfx[256];
    __shared__ int startg, tbase, tottiles;
    if (t < 64) cnt[t] = 0;
    __syncthreads();

    int base = t * 32;
    int gl[32];
    int my = 0;
    #pragma unroll
    for (int k = 0; k < 32; k++) {
        gl[k] = g_tok[base + k];
        my += (gl[k] == g);
    }
    #pragma unroll
    for (int k = 0; k < 32; k++) atomicAdd(&cnt[gl[k]], 1);
    pfx[t] = my;
    __syncthreads();

    if (t == 0) {
        int run = 0, tb = 0, tt = 0;
        for (int gg = 0; gg < 64; gg++) {
            int c = cnt[gg];
            int ntl = (c + MT - 1) / MT;
            if (gg < g) { run += c; tb += ntl; }
            tt += ntl;
        }
        startg = run; tbase = tb; tottiles = tt;
    }
    // inclusive scan over 256 thread-counts (Hillis-Steele)
    for (int off = 1; off < 256; off <<= 1) {
        int add = (t >= off) ? pfx[t - off] : 0;
        __syncthreads();
        pfx[t] += add;
        __syncthreads();
    }

    int pos = startg + pfx[t] - my;   // exclusive prefix within bucket g
    #pragma unroll
    for (int k = 0; k < 32; k++) {
        if (gl[k] == g) {
            int idx = base + k;
            token_list[pos] = idx;
            wA_s[pos] = wA_tok[idx];
            wB_s[pos] = wB_tok[idx];
            pos++;
        }
    }
    if (t == 0) {
        int c = cnt[g];
        int off2 = 0, ti = tbase;
        while (off2 < c) {
            int rows = (c - off2 < MT) ? (c - off2) : MT;
            tile_desc[ti++] = make_int4(startg + off2, rows, g >> 3, g & 7);
            off2 += MT;
        }
        if (g == 0) *n_tiles_out = tottiles;
    }
}

// ---------------- Phase 3: grouped GEMM — 2-buffer pipeline (3 blocks/CU), counted vmcnt, XOR swizzle ----------------
// Grid dim3(8, tiles): XCD = colblk -> each XCD holds a fixed 128-col slice of all experts (L2-resident B).
// Half a (ks 0..15): B = expert ea;  half b (ks 16..31): B = expert ebx, same A addresses (L2 hit).
__global__ __launch_bounds__(256, 3) void moe_gemm(const unsigned short* __restrict__ Abf,
                                                   const unsigned short* __restrict__ WeT,
                                                   const int* __restrict__ token_list,
                                                   const float* __restrict__ wA_s,
                                                   const float* __restrict__ wB_s,
                                                   const int4* __restrict__ tile_desc,
                                                   const int* __restrict__ n_tiles,
                                                   float* __restrict__ out) {
    int tile = blockIdx.y;
    if (tile >= *n_tiles) return;
    int4 dsc = tile_desc[tile];
    int loff = dsc.x, rows = dsc.y, ea = dsc.z, ebx = dsc.w;
    int ncol0 = blockIdx.x * NT;

    __shared__ __align__(16) unsigned short lds[2 * BUF_S];  // 48 KB
    __shared__ int tokOut[MT];
    __shared__ int tokStage[MT];
    __shared__ float rat[MT], wBsh[MT];

    int t = threadIdx.x;
    int wave = t >> 6, lane = t & 63;

    if (t < MT) {
        int idx = loff + ((t < rows) ? t : 0);
        int tk = token_list[idx];
        tokStage[t] = tk;
        tokOut[t] = (t < rows) ? tk : -1;
        float wa = wA_s[idx], wb = wB_s[idx];
        wBsh[t] = wb;
        rat[t] = wa / fmaxf(wb, 1e-30f);
    }
    __syncthreads();

    // per-thread staging sources (swizzle folded into global address; LDS dest stays linear)
    int swz8 = (((t & 7) ^ ((t >> 3) & 7)) << 3);
    const unsigned short* asrc0 = Abf + (size_t)tokStage[t >> 3] * D_ + swz8;
    const unsigned short* asrc1 = Abf + (size_t)tokStage[32 + (t >> 3)] * D_ + swz8;
    const unsigned short* wbase = WeT + ((size_t)ea << 20);
    size_t ebd = ((size_t)(ebx - ea)) << 20;
    const unsigned short* bsrc0 = wbase + (size_t)(ncol0 +  0 + (t >> 3)) * D_ + swz8;
    const unsigned short* bsrc1 = wbase + (size_t)(ncol0 + 32 + (t >> 3)) * D_ + swz8;
    const unsigned short* bsrc2 = wbase + (size_t)(ncol0 + 64 + (t >> 3)) * D_ + swz8;
    const unsigned short* bsrc3 = wbase + (size_t)(ncol0 + 96 + (t >> 3)) * D_ + swz8;

    int wu = wave * 512;   // wave-uniform LDS chunk base (shorts)
    auto stage = [&](int ks, int buf) {
        unsigned short* base = &lds[buf * BUF_S];
        int k0 = (ks & 15) * BK;
        size_t boff = (size_t)k0 + ((ks < 16) ? 0 : ebd);
        gload16(asrc0 + k0,   base + wu);
        gload16(asrc1 + k0,   base + 2048 + wu);
        gload16(bsrc0 + boff, base + 4096 + wu);
        gload16(bsrc1 + boff, base + 6144 + wu);
        gload16(bsrc2 + boff, base + 8192 + wu);
        gload16(bsrc3 + boff, base + 10240 + wu);
    };

    // wave grid 2(M) x 2(N); wave-tile 32x64
    int wm = (wave >> 1) * 32, wn = (wave & 1) * 64;
    int l15 = lane & 15, hi = lane >> 4, lo7 = lane & 7;
    int rA0 = (wm + l15) * BK;
    int rA1 = rA0 + 16 * BK;
    int cB0 = (wn + l15) * BK + 4096;
    int s0 = ((hi) ^ lo7) << 3;          // ksub 0 slot offset (shorts)
    int s1 = ((4 + hi) ^ lo7) << 3;      // ksub 1
    int q4 = hi * 4;

    f32x4 acc[2][4];
    #pragma unroll
    for (int m = 0; m < 2; m++)
        #pragma unroll
        for (int n = 0; n < 4; n++) acc[m][n] = (f32x4){0.f, 0.f, 0.f, 0.f};

    stage(0, 0);
    for (int ks = 0; ks < KSTEPS; ++ks) {
        if (ks < KSTEPS - 1) {
            stage(ks + 1, (ks + 1) & 1);
            asm volatile("s_waitcnt vmcnt(6)" ::: "memory");
        } else {
            asm volatile("s_waitcnt vmcnt(0)" ::: "memory");
        }
        __builtin_amdgcn_s_barrier();
        if (ks == 16) {
            // expert switch: acc_a *= wA/wB per row; epilogue multiplies by wB
            #pragma unroll
            for (int m = 0; m < 2; m++) {
                #pragma unroll
                for (int j = 0; j < 4; j++) {
                    float rr = rat[wm + m * 16 + q4 + j];
                    #pragma unroll
                    for (int n = 0; n < 4; n++) acc[m][n][j] *= rr;
                }
            }
        }
        const unsigned short* Ab = &lds[(ks & 1) * BUF_S];
        #pragma unroll
        for (int ksub = 0; ksub < 2; ++ksub) {
            int s = ksub ? s1 : s0;
            short8 a0 = *reinterpret_cast<const short8*>(&Ab[rA0 + s]);
            short8 a1 = *reinterpret_cast<const short8*>(&Ab[rA1 + s]);
            #pragma unroll
            for (int n = 0; n < 4; n++) {
                short8 bfr = *reinterpret_cast<const short8*>(&Ab[cB0 + n * (16 * BK) + s]);
                acc[0][n] = __builtin_amdgcn_mfma_f32_16x16x32_bf16(a0, bfr, acc[0][n], 0, 0, 0);
                acc[1][n] = __builtin_amdgcn_mfma_f32_16x16x32_bf16(a1, bfr, acc[1][n], 0, 0, 0);
            }
        }
        __builtin_amdgcn_s_barrier();   // readers done before next iter's stage overwrites other buffer
    }

    // epilogue: single writer per out row; out = acc * wB
    #pragma unroll
    for (int m = 0; m < 2; m++) {
        #pragma unroll
        for (int n = 0; n < 4; n++) {
            int col = ncol0 + wn + n * 16 + l15;
            #pragma unroll
            for (int j = 0; j < 4; j++) {
                int r = wm + m * 16 + q4 + j;
                int tk = tokOut[r];
                if (tk >= 0) out[(size_t)tk * D_ + col] = acc[m][n][j] * wBsh[r];
            }
        }
    }
}

extern "C" void kernel_launch(void* const* d_in, const int* in_sizes, int n_in,
                              void* d_out, int out_size, void* d_ws, size_t ws_size,
                              hipStream_t stream) {
    const float* x  = (const float*)d_in[0];
    const float* Wg = (const float*)d_in[1];
    const float* We = (const float*)d_in[2];
    float* out = (float*)d_out;

    size_t off = 0;
    auto alloc = [&](size_t bytes) -> void* {
        void* p = (char*)d_ws + off;
        off += (bytes + 255) & ~(size_t)255;
        return p;
    };
    unsigned short* WeT  = (unsigned short*)alloc((size_t)E_ * 1024 * 1024 * 2);  // 16 MB
    unsigned short* Abf  = (unsigned short*)alloc((size_t)NTOK * D_ * 2);         // 16.8 MB
    int*   g_tok      = (int*)  alloc(NTOK * 4);
    float* wA_tok     = (float*)alloc(NTOK * 4);
    float* wB_tok     = (float*)alloc(NTOK * 4);
    int*   token_list = (int*)  alloc(NTOK * 4);
    float* wA_s       = (float*)alloc(NTOK * 4);
    float* wB_s       = (float*)alloc(NTOK * 4);
    int4*  tile_desc  = (int4*) alloc(MAX_TILES * 16);
    int*   n_tiles    = (int*)  alloc(4);

    prep_kernel<<<2048 + 256, 256, 0, stream>>>(We, WeT, x, Wg, g_tok, wA_tok, wB_tok, Abf);
    route_kernel<<<64, 256, 0, stream>>>(g_tok, wA_tok, wB_tok,
                                         token_list, wA_s, wB_s, tile_desc, n_tiles);
    moe_gemm<<<dim3(8, MAX_TILES), 256, 0, stream>>>(Abf, WeT, token_list, wA_s, wB_s,
                                                     tile_desc, n_tiles, out);
}